// Round 8
// baseline (491.762 us; speedup 1.0000x reference)
//
#include <hip/hip_runtime.h>
#include <cstdint>
#include <cstddef>

// Problem constants
#define B_   4
#define S_   2048
#define HID_ 768
#define H_   12
#define D_   64
#define BH_  (B_*H_)        // 48
#define M1_  (B_*S_)        // 8192
#define N1_  (3*HID_)       // 2304
#define PWR  65.5f          // D + alpha

typedef _Float16 f16;
using half8    = __attribute__((ext_vector_type(8))) _Float16;
using float4_t = __attribute__((ext_vector_type(4))) float;

__device__ __forceinline__ float fexp2(float x) { return __builtin_amdgcn_exp2f(x); }
__device__ __forceinline__ float flog2(float x) { return __builtin_amdgcn_logf(x); }
__device__ __forceinline__ float fsqrt(float x) { return __builtin_amdgcn_sqrtf(x); }

// ---------------------------------------------------------------------------
__global__ __launch_bounds__(256) void k_convert_x(const float* __restrict__ x,
                                                   f16* __restrict__ xh) {
  int i = blockIdx.x * 256 + threadIdx.x;
  const float4* xv = (const float4*)x;
  float4 v = xv[i];
  f16 tmp[4] = {(f16)v.x, (f16)v.y, (f16)v.z, (f16)v.w};
  *(uint2*)(xh + 4 * (size_t)i) = *(uint2*)tmp;
}

__global__ __launch_bounds__(256) void k_transpose_w(const float* __restrict__ w,
                                                     f16* __restrict__ wt,
                                                     int N, int K) {
  int n = blockIdx.x * 256 + threadIdx.x;
  int k = blockIdx.y;
  if (n < N) wt[(size_t)n * K + k] = (f16)w[(size_t)k * N + n];
}

// ---------------------------------------------------------------------------
__global__ __launch_bounds__(256) void k_gemm_qkv(
    const f16* __restrict__ A, const f16* __restrict__ Bt,
    const float* __restrict__ bias,
    f16* __restrict__ Qh, f16* __restrict__ Kh, f16* __restrict__ Vt) {
  __shared__ f16 As[128][72];
  __shared__ f16 Bs[128][72];
  int tid  = threadIdx.x;
  int wave = tid >> 6, lane = tid & 63;
  int quad = lane >> 4, l15 = lane & 15;
  int wm = wave >> 1, wn = wave & 1;
  int m0 = blockIdx.y * 128;
  int n0 = blockIdx.x * 128;

  float4_t acc[4][4] = {};
  int r  = tid >> 3;
  int c8 = (tid & 7) * 8;

  for (int k0 = 0; k0 < 768; k0 += 64) {
    for (int rr = 0; rr < 128; rr += 32) {
      *(uint4*)(&As[r + rr][c8]) =
          *(const uint4*)(A  + (size_t)(m0 + r + rr) * 768 + k0 + c8);
      *(uint4*)(&Bs[r + rr][c8]) =
          *(const uint4*)(Bt + (size_t)(n0 + r + rr) * 768 + k0 + c8);
    }
    __syncthreads();
    half8 af[4][2], bf[4][2];
    for (int mt = 0; mt < 4; mt++)
      for (int ks = 0; ks < 2; ks++)
        af[mt][ks] = *(const half8*)(&As[wm * 64 + mt * 16 + l15][ks * 32 + quad * 8]);
    for (int nt = 0; nt < 4; nt++)
      for (int ks = 0; ks < 2; ks++)
        bf[nt][ks] = *(const half8*)(&Bs[wn * 64 + nt * 16 + l15][ks * 32 + quad * 8]);
    for (int ks = 0; ks < 2; ks++)
      for (int mt = 0; mt < 4; mt++)
        for (int nt = 0; nt < 4; nt++)
          acc[mt][nt] = __builtin_amdgcn_mfma_f32_16x16x32_f16(af[mt][ks], bf[nt][ks],
                                                               acc[mt][nt], 0, 0, 0);
    __syncthreads();
  }

  for (int mt = 0; mt < 4; mt++)
    for (int nt = 0; nt < 4; nt++)
      for (int rg = 0; rg < 4; rg++) {
        int R = m0 + wm * 64 + mt * 16 + quad * 4 + rg;
        int n = n0 + wn * 64 + nt * 16 + l15;
        float v = acc[mt][nt][rg] + bias[n];
        int b = R >> 11, s = R & 2047;
        int which = n / 768;
        int rem = n - which * 768;
        int h = rem >> 6, d = rem & 63;
        int bh = b * 12 + h;
        f16 hv = (f16)v;
        if (which == 0)      Qh[((size_t)bh * 2048 + s) * 64 + d] = hv;
        else if (which == 1) Kh[((size_t)bh * 2048 + s) * 64 + d] = hv;
        else                 Vt[((size_t)bh * 64 + d) * 2048 + s] = hv;
      }
}

// ---------------------------------------------------------------------------
__global__ __launch_bounds__(256) void k_norms(const f16* __restrict__ Qh,
                                               const f16* __restrict__ Kh,
                                               float* __restrict__ qq,
                                               float* __restrict__ kk) {
  int i = blockIdx.x * 256 + threadIdx.x;
  if (i >= BH_ * S_) return;
  const f16* p = Qh + (size_t)i * 64;
  float s1 = 0.f, s2 = 0.f;
  for (int d = 0; d < 64; d += 8) {
    half8 v = *(const half8*)(p + d);
    for (int j = 0; j < 8; j++) { float t = (float)v[j]; s1 += t * t; }
  }
  p = Kh + (size_t)i * 64;
  for (int d = 0; d < 64; d += 8) {
    half8 v = *(const half8*)(p + d);
    for (int j = 0; j < 8; j++) { float t = (float)v[j]; s2 += t * t; }
  }
  qq[i] = s1;
  kk[i] = s2;
}

// ---------------------------------------------------------------------------
// Pass 1: column logsumexp. 128-column j-tile (K resident in LDS, Q streams).
// Lazy online max via running min-d2 (c monotone in d2). 2 barriers/iter.
__global__ __launch_bounds__(256, 4) void k_colsum(
    const f16* __restrict__ Qh, const f16* __restrict__ Kh,
    const float* __restrict__ qq, const float* __restrict__ kk,
    float* __restrict__ lognc) {
  int bh = blockIdx.y;
  int j0 = blockIdx.x * 128;
  __shared__ __align__(16) char smem[28416];
  f16 (*Kt)[72] = (f16(*)[72])smem;                    // [128][72] resident
  f16 (*Qt)[72] = (f16(*)[72])(smem + 18432);          // [64][72] streamed
  float* kks = (float*)(smem + 18432 + 9216);          // [128]
  float* qqs = kks + 128;                              // [64]

  int tid = threadIdx.x;
  int wave = tid >> 6, lane = tid & 63, quad = lane >> 4, l15 = lane & 15;
  int r = tid >> 3, c8 = (tid & 7) * 8;
  const f16* Kb = Kh + (size_t)bh * 2048 * 64;
  const f16* Qb = Qh + (size_t)bh * 2048 * 64;

  for (int rr = 0; rr < 128; rr += 32)
    *(uint4*)(&Kt[r + rr][c8]) = *(const uint4*)(Kb + (size_t)(j0 + r + rr) * 64 + c8);
  if (tid < 128) kks[tid] = kk[bh * 2048 + j0 + tid];
  __syncthreads();

  half8 af[2][2];
  float kkv[2][4];
  for (int s = 0; s < 2; s++) {
    for (int ks = 0; ks < 2; ks++)
      af[s][ks] = *(const half8*)(&Kt[s * 64 + wave * 16 + l15][ks * 32 + quad * 8]);
    for (int t = 0; t < 4; t++) kkv[s][t] = kks[s * 64 + wave * 16 + quad * 4 + t];
  }

  float rm[2][4], rmind2[2][4], rs[2][4];
  for (int s = 0; s < 2; s++)
    for (int t = 0; t < 4; t++) { rm[s][t] = -1e30f; rmind2[s][t] = 1e30f; rs[s][t] = 0.f; }

  for (int it = 0; it < 32; it++) {
    __syncthreads();
    int i0 = it * 64;
    for (int rr = 0; rr < 64; rr += 32)
      *(uint4*)(&Qt[r + rr][c8]) = *(const uint4*)(Qb + (size_t)(i0 + r + rr) * 64 + c8);
    if (tid < 64) qqs[tid] = qq[bh * 2048 + i0 + tid];
    __syncthreads();

    for (int s = 0; s < 2; s++) {
      float4_t acc[4] = {};
      for (int nt = 0; nt < 4; nt++)
        for (int ks = 0; ks < 2; ks++) {
          half8 bfv = *(const half8*)(&Qt[nt * 16 + l15][ks * 32 + quad * 8]);
          acc[nt] = __builtin_amdgcn_mfma_f32_16x16x32_f16(af[s][ks], bfv, acc[nt], 0, 0, 0);
        }

      float d2v[4][4];
      float lmn[4] = {1e30f, 1e30f, 1e30f, 1e30f};
      for (int nt = 0; nt < 4; nt++) {
        float qn = qqs[nt * 16 + l15];
        for (int rg = 0; rg < 4; rg++) {
          float d2 = fmaxf(fmaf(-2.f, acc[nt][rg], kkv[s][rg] + qn), 0.f);
          d2v[nt][rg] = d2;
          lmn[rg] = fminf(lmn[rg], d2);
        }
      }
      bool noimp = (lmn[0] >= rmind2[s][0]) & (lmn[1] >= rmind2[s][1]) &
                   (lmn[2] >= rmind2[s][2]) & (lmn[3] >= rmind2[s][3]);
      if (!__all(noimp)) {
        for (int rg = 0; rg < 4; rg++) {
          float t = lmn[rg];
          for (int m = 1; m < 16; m <<= 1) t = fminf(t, __shfl_xor(t, m, 16));
          t = fminf(t, rmind2[s][rg]);
          float nm = -PWR * flog2(1.f + fsqrt(t));
          rs[s][rg] *= fexp2(rm[s][rg] - nm);
          rm[s][rg] = nm; rmind2[s][rg] = t;
        }
      }
      for (int nt = 0; nt < 4; nt++)
        for (int rg = 0; rg < 4; rg++) {
          float g = fsqrt(d2v[nt][rg]);
          rs[s][rg] += fexp2(fmaf(-PWR, flog2(1.f + g), -rm[s][rg]));
        }
    }
  }
  for (int s = 0; s < 2; s++)
    for (int rg = 0; rg < 4; rg++) {
      float t = rs[s][rg];
      for (int m = 1; m < 16; m <<= 1) t += __shfl_xor(t, m, 16);
      if (l15 == 0) {
        int j = j0 + s * 64 + wave * 16 + quad * 4 + rg;
        lognc[bh * 2048 + j] = rm[s][rg] + flog2(t);
      }
    }
}

// ---------------------------------------------------------------------------
// Pass 2: flash, 128-row i-tile (2 sub-tiles/wave). 2 barriers/iter: the P
// LDS round-trip is per-wave (cross-lane within one wave) -> ordered by
// lgkmcnt, no barrier needed. Qt overlays Kt+Vts (Qt dead after frag load).
__global__ __launch_bounds__(256, 4) void k_flash(
    const f16* __restrict__ Qh, const f16* __restrict__ Kh, const f16* __restrict__ Vt,
    const float* __restrict__ qq, const float* __restrict__ kk,
    const float* __restrict__ lognc, f16* __restrict__ attn) {
  int bh = blockIdx.y;
  int i0 = blockIdx.x * 128;
  __shared__ __align__(16) char smem[28672];
  f16 (*Qt)[72]  = (f16(*)[72])smem;                   // [128][72], start only
  f16 (*Kt)[72]  = (f16(*)[72])smem;                   // [64][72] per iter
  f16 (*Vts)[72] = (f16(*)[72])(smem + 9216);          // [64][72] per iter
  f16 (*PldsAll)[72] = (f16(*)[72])(smem + 18432);     // [64][72]: 16 rows/wave
  float* qqs = (float*)(smem + 18432 + 9216);          // [128]
  float* kks = qqs + 128;                              // [64]
  float* lns = kks + 64;                               // [64]

  int tid = threadIdx.x;
  int wave = tid >> 6, lane = tid & 63, quad = lane >> 4, l15 = lane & 15;
  int r = tid >> 3, c8 = (tid & 7) * 8;
  f16 (*Pw)[72] = PldsAll + wave * 16;                 // this wave's P tile
  const f16* Qb = Qh + (size_t)bh * 2048 * 64;
  const f16* Kb = Kh + (size_t)bh * 2048 * 64;
  const f16* Vb = Vt + (size_t)bh * 64 * 2048;

  for (int rr = 0; rr < 128; rr += 32)
    *(uint4*)(&Qt[r + rr][c8]) = *(const uint4*)(Qb + (size_t)(i0 + r + rr) * 64 + c8);
  if (tid < 128) qqs[tid] = qq[bh * 2048 + i0 + tid];
  __syncthreads();

  half8 af[2][2];
  float qv[2][4];
  for (int s = 0; s < 2; s++) {
    for (int ks = 0; ks < 2; ks++)
      af[s][ks] = *(const half8*)(&Qt[s * 64 + wave * 16 + l15][ks * 32 + quad * 8]);
    for (int t = 0; t < 4; t++) qv[s][t] = qqs[s * 64 + wave * 16 + quad * 4 + t];
  }

  float rm[2][4], os[2][4];
  float4_t Oacc[2][4] = {};
  for (int s = 0; s < 2; s++)
    for (int t = 0; t < 4; t++) { rm[s][t] = -1e30f; os[s][t] = 0.f; }

  for (int jt = 0; jt < 32; jt++) {
    __syncthreads();   // prev iter's Kt/Vts reads done (also Qt reads, jt=0)
    int j0 = jt * 64;
    for (int rr = 0; rr < 64; rr += 32) {
      *(uint4*)(&Kt[r + rr][c8]) =
          *(const uint4*)(Kb + (size_t)(j0 + r + rr) * 64 + c8);
      *(uint4*)(&Vts[r + rr][c8]) =
          *(const uint4*)(Vb + (size_t)(r + rr) * 2048 + j0 + c8);
    }
    if (tid < 64) {
      kks[tid] = kk[bh * 2048 + j0 + tid];
      lns[tid] = -0.5f * lognc[bh * 2048 + j0 + tid];
    }
    __syncthreads();

    for (int s = 0; s < 2; s++) {
      float4_t acc[4] = {};
      for (int nt = 0; nt < 4; nt++)
        for (int ks = 0; ks < 2; ks++) {
          half8 bfv = *(const half8*)(&Kt[nt * 16 + l15][ks * 32 + quad * 8]);
          acc[nt] = __builtin_amdgcn_mfma_f32_16x16x32_f16(af[s][ks], bfv, acc[nt], 0, 0, 0);
        }

      float mv[4][4];
      float lmx[4] = {-1e30f, -1e30f, -1e30f, -1e30f};
      for (int nt = 0; nt < 4; nt++) {
        float kn = kks[nt * 16 + l15];
        float bias = lns[nt * 16 + l15];
        for (int rg = 0; rg < 4; rg++) {
          float d2 = fmaxf(fmaf(-2.f, acc[nt][rg], qv[s][rg] + kn), 0.f);
          float g = fsqrt(d2);
          float m = fmaf(-PWR, flog2(1.f + g), bias);
          mv[nt][rg] = m;
          lmx[rg] = fmaxf(lmx[rg], m);
        }
      }
      bool noimp = (lmx[0] <= rm[s][0]) & (lmx[1] <= rm[s][1]) &
                   (lmx[2] <= rm[s][2]) & (lmx[3] <= rm[s][3]);
      if (!__all(noimp)) {
        for (int rg = 0; rg < 4; rg++) {
          float t = lmx[rg];
          for (int m = 1; m < 16; m <<= 1) t = fmaxf(t, __shfl_xor(t, m, 16));
          t = fmaxf(t, rm[s][rg]);
          float a = fexp2(rm[s][rg] - t);
          os[s][rg] *= a;
          Oacc[s][0][rg] *= a; Oacc[s][1][rg] *= a;
          Oacc[s][2][rg] *= a; Oacc[s][3][rg] *= a;
          rm[s][rg] = t;
        }
      }

      for (int nt = 0; nt < 4; nt++)
        for (int rg = 0; rg < 4; rg++) {
          float p = fexp2(mv[nt][rg] - rm[s][rg]);   // <= 1 guaranteed
          os[s][rg] += p;
          Pw[quad * 4 + rg][nt * 16 + l15] = (f16)p;
        }
      // no barrier: Pw is this wave's private tile; lgkmcnt orders write->read

      for (int ks = 0; ks < 2; ks++) {
        half8 pa = *(const half8*)(&Pw[l15][ks * 32 + quad * 8]);
        for (int nt = 0; nt < 4; nt++) {
          half8 vbv = *(const half8*)(&Vts[nt * 16 + l15][ks * 32 + quad * 8]);
          Oacc[s][nt] = __builtin_amdgcn_mfma_f32_16x16x32_f16(pa, vbv, Oacc[s][nt], 0, 0, 0);
        }
      }
    }
  }

  int b = bh / 12, h = bh - b * 12;
  for (int s = 0; s < 2; s++)
    for (int rg = 0; rg < 4; rg++) {
      float t = os[s][rg];
      for (int m = 1; m < 16; m <<= 1) t += __shfl_xor(t, m, 16);
      float inv = 1.f / t;
      int srow = i0 + s * 64 + wave * 16 + quad * 4 + rg;
      for (int nt = 0; nt < 4; nt++) {
        int d = nt * 16 + l15;
        attn[((size_t)(b * 2048 + srow)) * 768 + h * 64 + d] =
            (f16)(Oacc[s][nt][rg] * inv);
      }
    }
}

// ---------------------------------------------------------------------------
__global__ __launch_bounds__(256) void k_gemm_out(
    const f16* __restrict__ A, const f16* __restrict__ Bt,
    const float* __restrict__ bias, float* __restrict__ out) {
  __shared__ f16 As[128][72];
  __shared__ f16 Bs[128][72];
  int tid  = threadIdx.x;
  int wave = tid >> 6, lane = tid & 63;
  int quad = lane >> 4, l15 = lane & 15;
  int wm = wave >> 1, wn = wave & 1;
  int m0 = blockIdx.y * 128;
  int n0 = blockIdx.x * 128;

  float4_t acc[4][4] = {};
  int r  = tid >> 3;
  int c8 = (tid & 7) * 8;

  for (int k0 = 0; k0 < 768; k0 += 64) {
    for (int rr = 0; rr < 128; rr += 32) {
      *(uint4*)(&As[r + rr][c8]) =
          *(const uint4*)(A  + (size_t)(m0 + r + rr) * 768 + k0 + c8);
      *(uint4*)(&Bs[r + rr][c8]) =
          *(const uint4*)(Bt + (size_t)(n0 + r + rr) * 768 + k0 + c8);
    }
    __syncthreads();
    half8 af[4][2], bf[4][2];
    for (int mt = 0; mt < 4; mt++)
      for (int ks = 0; ks < 2; ks++)
        af[mt][ks] = *(const half8*)(&As[wm * 64 + mt * 16 + l15][ks * 32 + quad * 8]);
    for (int nt = 0; nt < 4; nt++)
      for (int ks = 0; ks < 2; ks++)
        bf[nt][ks] = *(const half8*)(&Bs[wn * 64 + nt * 16 + l15][ks * 32 + quad * 8]);
    for (int ks = 0; ks < 2; ks++)
      for (int mt = 0; mt < 4; mt++)
        for (int nt = 0; nt < 4; nt++)
          acc[mt][nt] = __builtin_amdgcn_mfma_f32_16x16x32_f16(af[mt][ks], bf[nt][ks],
                                                               acc[mt][nt], 0, 0, 0);
    __syncthreads();
  }

  for (int mt = 0; mt < 4; mt++)
    for (int nt = 0; nt < 4; nt++)
      for (int rg = 0; rg < 4; rg++) {
        int R = m0 + wm * 64 + mt * 16 + quad * 4 + rg;
        int n = n0 + wn * 64 + nt * 16 + l15;
        out[(size_t)R * 768 + n] = acc[mt][nt][rg] + bias[n];
      }
}

// ---------------------------------------------------------------------------
extern "C" void kernel_launch(void* const* d_in, const int* in_sizes, int n_in,
                              void* d_out, int out_size, void* d_ws, size_t ws_size,
                              hipStream_t stream) {
  const float* x     = (const float*)d_in[0];
  const float* Wqkv  = (const float*)d_in[1];
  const float* bqkv  = (const float*)d_in[2];
  const float* Wout  = (const float*)d_in[3];
  const float* bout  = (const float*)d_in[4];
  float* out = (float*)d_out;

  char* ws = (char*)d_ws;
  size_t off = 0;
  f16* xh     = (f16*)(ws + off);
  off += (size_t)M1_ * HID_ * 2;
  f16* wqkvt  = (f16*)(ws + off); off += (size_t)N1_ * HID_ * 2;
  f16* woutt  = (f16*)(ws + off); off += (size_t)HID_ * HID_ * 2;
  f16* Qh     = (f16*)(ws + off); off += (size_t)BH_ * S_ * D_ * 2;
  f16* Kh     = (f16*)(ws + off); off += (size_t)BH_ * S_ * D_ * 2;
  f16* Vt     = (f16*)(ws + off); off += (size_t)BH_ * S_ * D_ * 2;
  float* qq   = (float*)(ws + off); off += (size_t)BH_ * S_ * 4;
  float* kk   = (float*)(ws + off); off += (size_t)BH_ * S_ * 4;
  float* lognc= (float*)(ws + off); off += (size_t)BH_ * S_ * 4;
  f16* attn   = xh;  // xh dead after k_gemm_qkv

  k_convert_x<<<dim3(M1_ * HID_ / 4 / 256), dim3(256), 0, stream>>>(x, xh);
  k_transpose_w<<<dim3(9, 768), dim3(256), 0, stream>>>(Wqkv, wqkvt, N1_, HID_);
  k_transpose_w<<<dim3(3, 768), dim3(256), 0, stream>>>(Wout, woutt, HID_, HID_);

  k_gemm_qkv<<<dim3(N1_ / 128, M1_ / 128), dim3(256), 0, stream>>>(
      xh, wqkvt, bqkv, Qh, Kh, Vt);

  k_norms<<<dim3(BH_ * S_ / 256), dim3(256), 0, stream>>>(Qh, Kh, qq, kk);

  k_colsum<<<dim3(S_ / 128, BH_), dim3(256), 0, stream>>>(Qh, Kh, qq, kk, lognc);

  k_flash<<<dim3(S_ / 128, BH_), dim3(256), 0, stream>>>(
      Qh, Kh, Vt, qq, kk, lognc, attn);

  k_gemm_out<<<dim3(HID_ / 128, M1_ / 128), dim3(256), 0, stream>>>(
      attn, woutt, bout, out);
}

// Round 9
// 483.545 us; speedup vs baseline: 1.0170x; 1.0170x over previous
//
#include <hip/hip_runtime.h>
#include <cstdint>
#include <cstddef>

// Problem constants
#define B_   4
#define S_   2048
#define HID_ 768
#define H_   12
#define D_   64
#define BH_  (B_*H_)        // 48
#define M1_  (B_*S_)        // 8192
#define N1_  (3*HID_)       // 2304
#define PWR  65.5f          // D + alpha

typedef _Float16 f16;
using half8    = __attribute__((ext_vector_type(8))) _Float16;
using float4_t = __attribute__((ext_vector_type(4))) float;

__device__ __forceinline__ float fexp2(float x) { return __builtin_amdgcn_exp2f(x); }
__device__ __forceinline__ float flog2(float x) { return __builtin_amdgcn_logf(x); }
__device__ __forceinline__ float fsqrt(float x) { return __builtin_amdgcn_sqrtf(x); }

// ---------------------------------------------------------------------------
__global__ __launch_bounds__(256) void k_convert_x(const float* __restrict__ x,
                                                   f16* __restrict__ xh) {
  int i = blockIdx.x * 256 + threadIdx.x;
  const float4* xv = (const float4*)x;
  float4 v = xv[i];
  f16 tmp[4] = {(f16)v.x, (f16)v.y, (f16)v.z, (f16)v.w};
  *(uint2*)(xh + 4 * (size_t)i) = *(uint2*)tmp;
}

__global__ __launch_bounds__(256) void k_transpose_w(const float* __restrict__ w,
                                                     f16* __restrict__ wt,
                                                     int N, int K) {
  int n = blockIdx.x * 256 + threadIdx.x;
  int k = blockIdx.y;
  if (n < N) wt[(size_t)n * K + k] = (f16)w[(size_t)k * N + n];
}

// ---------------------------------------------------------------------------
__global__ __launch_bounds__(256) void k_gemm_qkv(
    const f16* __restrict__ A, const f16* __restrict__ Bt,
    const float* __restrict__ bias,
    f16* __restrict__ Qh, f16* __restrict__ Kh, f16* __restrict__ Vt) {
  __shared__ f16 As[128][72];
  __shared__ f16 Bs[128][72];
  int tid  = threadIdx.x;
  int wave = tid >> 6, lane = tid & 63;
  int quad = lane >> 4, l15 = lane & 15;
  int wm = wave >> 1, wn = wave & 1;
  int m0 = blockIdx.y * 128;
  int n0 = blockIdx.x * 128;

  float4_t acc[4][4] = {};
  int r  = tid >> 3;
  int c8 = (tid & 7) * 8;

  for (int k0 = 0; k0 < 768; k0 += 64) {
    for (int rr = 0; rr < 128; rr += 32) {
      *(uint4*)(&As[r + rr][c8]) =
          *(const uint4*)(A  + (size_t)(m0 + r + rr) * 768 + k0 + c8);
      *(uint4*)(&Bs[r + rr][c8]) =
          *(const uint4*)(Bt + (size_t)(n0 + r + rr) * 768 + k0 + c8);
    }
    __syncthreads();
    half8 af[4][2], bf[4][2];
    for (int mt = 0; mt < 4; mt++)
      for (int ks = 0; ks < 2; ks++)
        af[mt][ks] = *(const half8*)(&As[wm * 64 + mt * 16 + l15][ks * 32 + quad * 8]);
    for (int nt = 0; nt < 4; nt++)
      for (int ks = 0; ks < 2; ks++)
        bf[nt][ks] = *(const half8*)(&Bs[wn * 64 + nt * 16 + l15][ks * 32 + quad * 8]);
    for (int ks = 0; ks < 2; ks++)
      for (int mt = 0; mt < 4; mt++)
        for (int nt = 0; nt < 4; nt++)
          acc[mt][nt] = __builtin_amdgcn_mfma_f32_16x16x32_f16(af[mt][ks], bf[nt][ks],
                                                               acc[mt][nt], 0, 0, 0);
    __syncthreads();
  }

  for (int mt = 0; mt < 4; mt++)
    for (int nt = 0; nt < 4; nt++)
      for (int rg = 0; rg < 4; rg++) {
        int R = m0 + wm * 64 + mt * 16 + quad * 4 + rg;
        int n = n0 + wn * 64 + nt * 16 + l15;
        float v = acc[mt][nt][rg] + bias[n];
        int b = R >> 11, s = R & 2047;
        int which = n / 768;
        int rem = n - which * 768;
        int h = rem >> 6, d = rem & 63;
        int bh = b * 12 + h;
        f16 hv = (f16)v;
        if (which == 0)      Qh[((size_t)bh * 2048 + s) * 64 + d] = hv;
        else if (which == 1) Kh[((size_t)bh * 2048 + s) * 64 + d] = hv;
        else                 Vt[((size_t)bh * 64 + d) * 2048 + s] = hv;
      }
}

// ---------------------------------------------------------------------------
__global__ __launch_bounds__(256) void k_norms(const f16* __restrict__ Qh,
                                               const f16* __restrict__ Kh,
                                               float* __restrict__ qq,
                                               float* __restrict__ kk) {
  int i = blockIdx.x * 256 + threadIdx.x;
  if (i >= BH_ * S_) return;
  const f16* p = Qh + (size_t)i * 64;
  float s1 = 0.f, s2 = 0.f;
  for (int d = 0; d < 64; d += 8) {
    half8 v = *(const half8*)(p + d);
    for (int j = 0; j < 8; j++) { float t = (float)v[j]; s1 += t * t; }
  }
  p = Kh + (size_t)i * 64;
  for (int d = 0; d < 64; d += 8) {
    half8 v = *(const half8*)(p + d);
    for (int j = 0; j < 8; j++) { float t = (float)v[j]; s2 += t * t; }
  }
  qq[i] = s1;
  kk[i] = s2;
}

// ---------------------------------------------------------------------------
// Pass 1: column logsumexp. 64-col j-tile (K resident), Q streamed with
// register double-buffer. Lazy online max via running min-d2.
__global__ __launch_bounds__(256, 6) void k_colsum(
    const f16* __restrict__ Qh, const f16* __restrict__ Kh,
    const float* __restrict__ qq, const float* __restrict__ kk,
    float* __restrict__ lognc) {
  int bh = blockIdx.y;
  int j0 = blockIdx.x * 64;
  __shared__ __align__(16) char smem[18944];
  f16 (*Kt)[72] = (f16(*)[72])smem;            // [64][72] resident
  f16 (*Qt)[72] = (f16(*)[72])(smem + 9216);   // [64][72] streamed
  float* kks = (float*)(smem + 18432);         // [64]
  float* qqs = kks + 64;                       // [64]

  int tid = threadIdx.x;
  int wave = tid >> 6, lane = tid & 63, quad = lane >> 4, l15 = lane & 15;
  int r = tid >> 3, c8 = (tid & 7) * 8;
  const f16* Kb = Kh + (size_t)bh * 2048 * 64;
  const f16* Qb = Qh + (size_t)bh * 2048 * 64;

  for (int rr = 0; rr < 64; rr += 32)
    *(uint4*)(&Kt[r + rr][c8]) = *(const uint4*)(Kb + (size_t)(j0 + r + rr) * 64 + c8);
  if (tid < 64) kks[tid] = kk[bh * 2048 + j0 + tid];
  __syncthreads();

  half8 af[2];
  for (int ks = 0; ks < 2; ks++)
    af[ks] = *(const half8*)(&Kt[wave * 16 + l15][ks * 32 + quad * 8]);
  float kkv[4];
  for (int t = 0; t < 4; t++) kkv[t] = kks[wave * 16 + quad * 4 + t];

  float rm[4], rmind2[4], rs[4];
  for (int t = 0; t < 4; t++) { rm[t] = -1e30f; rmind2[t] = 1e30f; rs[t] = 0.f; }

  // prefetch tile 0 into registers
  uint4 qreg0 = *(const uint4*)(Qb + (size_t)r * 64 + c8);
  uint4 qreg1 = *(const uint4*)(Qb + (size_t)(r + 32) * 64 + c8);
  float qqreg = (tid < 64) ? qq[bh * 2048 + tid] : 0.f;

  for (int it = 0; it < 32; it++) {
    __syncthreads();
    *(uint4*)(&Qt[r][c8])      = qreg0;
    *(uint4*)(&Qt[r + 32][c8]) = qreg1;
    if (tid < 64) qqs[tid] = qqreg;
    if (it + 1 < 32) {
      int i1 = (it + 1) * 64;
      qreg0 = *(const uint4*)(Qb + (size_t)(i1 + r) * 64 + c8);
      qreg1 = *(const uint4*)(Qb + (size_t)(i1 + r + 32) * 64 + c8);
      if (tid < 64) qqreg = qq[bh * 2048 + i1 + tid];
    }
    __syncthreads();

    float4_t acc[4] = {};
    for (int nt = 0; nt < 4; nt++)
      for (int ks = 0; ks < 2; ks++) {
        half8 bfv = *(const half8*)(&Qt[nt * 16 + l15][ks * 32 + quad * 8]);
        acc[nt] = __builtin_amdgcn_mfma_f32_16x16x32_f16(af[ks], bfv, acc[nt], 0, 0, 0);
      }

    float d2v[4][4];
    float lmn[4] = {1e30f, 1e30f, 1e30f, 1e30f};
    for (int nt = 0; nt < 4; nt++) {
      float qn = qqs[nt * 16 + l15];
      for (int rg = 0; rg < 4; rg++) {
        float d2 = fmaxf(fmaf(-2.f, acc[nt][rg], kkv[rg] + qn), 0.f);
        d2v[nt][rg] = d2;
        lmn[rg] = fminf(lmn[rg], d2);
      }
    }
    bool noimp = (lmn[0] >= rmind2[0]) & (lmn[1] >= rmind2[1]) &
                 (lmn[2] >= rmind2[2]) & (lmn[3] >= rmind2[3]);
    if (!__all(noimp)) {
      for (int rg = 0; rg < 4; rg++) {
        float t = lmn[rg];
        for (int m = 1; m < 16; m <<= 1) t = fminf(t, __shfl_xor(t, m, 16));
        t = fminf(t, rmind2[rg]);
        float nm = -PWR * flog2(1.f + fsqrt(t));
        rs[rg] *= fexp2(rm[rg] - nm);
        rm[rg] = nm; rmind2[rg] = t;
      }
    }
    for (int nt = 0; nt < 4; nt++)
      for (int rg = 0; rg < 4; rg++) {
        float g = fsqrt(d2v[nt][rg]);
        rs[rg] += fexp2(fmaf(-PWR, flog2(1.f + g), -rm[rg]));
      }
  }
  for (int rg = 0; rg < 4; rg++) {
    float s = rs[rg];
    for (int m = 1; m < 16; m <<= 1) s += __shfl_xor(s, m, 16);
    if (l15 == 0) {
      int j = j0 + wave * 16 + quad * 4 + rg;
      lognc[bh * 2048 + j] = rm[rg] + flog2(s);
    }
  }
}

// ---------------------------------------------------------------------------
// Pass 2: flash, 64-row i-tile. Qt overlays Kt (Qt dead after frag load).
// K/V streamed with register double-buffer. Wave-private P tile (no barrier).
__global__ __launch_bounds__(256, 5) void k_flash(
    const f16* __restrict__ Qh, const f16* __restrict__ Kh, const f16* __restrict__ Vt,
    const float* __restrict__ qq, const float* __restrict__ kk,
    const float* __restrict__ lognc, f16* __restrict__ attn) {
  int bh = blockIdx.y;
  int i0 = blockIdx.x * 64;
  __shared__ __align__(16) char smem[28416];
  f16 (*Qt)[72]  = (f16(*)[72])smem;            // [64][72], start only
  f16 (*Kt)[72]  = (f16(*)[72])smem;            // [64][72] per iter (overlay)
  f16 (*Vts)[72] = (f16(*)[72])(smem + 9216);   // [64][72] per iter
  f16 (*PldsAll)[72] = (f16(*)[72])(smem + 18432);  // [64][72]: 16 rows/wave
  float* qqs = (float*)(smem + 27648);          // [64]
  float* kks = qqs + 64;                        // [64]
  float* lns = kks + 64;                        // [64]

  int tid = threadIdx.x;
  int wave = tid >> 6, lane = tid & 63, quad = lane >> 4, l15 = lane & 15;
  int r = tid >> 3, c8 = (tid & 7) * 8;
  f16 (*Pw)[72] = PldsAll + wave * 16;
  const f16* Qb = Qh + (size_t)bh * 2048 * 64;
  const f16* Kb = Kh + (size_t)bh * 2048 * 64;
  const f16* Vb = Vt + (size_t)bh * 64 * 2048;

  for (int rr = 0; rr < 64; rr += 32)
    *(uint4*)(&Qt[r + rr][c8]) = *(const uint4*)(Qb + (size_t)(i0 + r + rr) * 64 + c8);
  if (tid < 64) qqs[tid] = qq[bh * 2048 + i0 + tid];
  __syncthreads();

  half8 af[2];
  for (int ks = 0; ks < 2; ks++)
    af[ks] = *(const half8*)(&Qt[wave * 16 + l15][ks * 32 + quad * 8]);
  float qv[4];
  for (int t = 0; t < 4; t++) qv[t] = qqs[wave * 16 + quad * 4 + t];

  float rm[4], os[4];
  float4_t Oacc[4] = {};
  for (int t = 0; t < 4; t++) { rm[t] = -1e30f; os[t] = 0.f; }

  // prefetch tile 0 into registers
  uint4 kreg0 = *(const uint4*)(Kb + (size_t)r * 64 + c8);
  uint4 kreg1 = *(const uint4*)(Kb + (size_t)(r + 32) * 64 + c8);
  uint4 vreg0 = *(const uint4*)(Vb + (size_t)r * 2048 + c8);
  uint4 vreg1 = *(const uint4*)(Vb + (size_t)(r + 32) * 2048 + c8);
  float kkreg = 0.f, lnreg = 0.f;
  if (tid < 64) {
    kkreg = kk[bh * 2048 + tid];
    lnreg = -0.5f * lognc[bh * 2048 + tid];
  }

  for (int jt = 0; jt < 32; jt++) {
    __syncthreads();   // prev compute done (incl. pre-loop Qt frag reads)
    *(uint4*)(&Kt[r][c8])       = kreg0;
    *(uint4*)(&Kt[r + 32][c8])  = kreg1;
    *(uint4*)(&Vts[r][c8])      = vreg0;
    *(uint4*)(&Vts[r + 32][c8]) = vreg1;
    if (tid < 64) { kks[tid] = kkreg; lns[tid] = lnreg; }
    if (jt + 1 < 32) {
      int j1 = (jt + 1) * 64;
      kreg0 = *(const uint4*)(Kb + (size_t)(j1 + r) * 64 + c8);
      kreg1 = *(const uint4*)(Kb + (size_t)(j1 + r + 32) * 64 + c8);
      vreg0 = *(const uint4*)(Vb + (size_t)r * 2048 + j1 + c8);
      vreg1 = *(const uint4*)(Vb + (size_t)(r + 32) * 2048 + j1 + c8);
      if (tid < 64) {
        kkreg = kk[bh * 2048 + j1 + tid];
        lnreg = -0.5f * lognc[bh * 2048 + j1 + tid];
      }
    }
    __syncthreads();

    float4_t acc[4] = {};
    for (int nt = 0; nt < 4; nt++)
      for (int ks = 0; ks < 2; ks++) {
        half8 bfv = *(const half8*)(&Kt[nt * 16 + l15][ks * 32 + quad * 8]);
        acc[nt] = __builtin_amdgcn_mfma_f32_16x16x32_f16(af[ks], bfv, acc[nt], 0, 0, 0);
      }

    float mv[4][4];
    float lmx[4] = {-1e30f, -1e30f, -1e30f, -1e30f};
    for (int nt = 0; nt < 4; nt++) {
      float kn = kks[nt * 16 + l15];
      float bias = lns[nt * 16 + l15];
      for (int rg = 0; rg < 4; rg++) {
        float d2 = fmaxf(fmaf(-2.f, acc[nt][rg], qv[rg] + kn), 0.f);
        float g = fsqrt(d2);
        float m = fmaf(-PWR, flog2(1.f + g), bias);
        mv[nt][rg] = m;
        lmx[rg] = fmaxf(lmx[rg], m);
      }
    }
    bool noimp = (lmx[0] <= rm[0]) & (lmx[1] <= rm[1]) &
                 (lmx[2] <= rm[2]) & (lmx[3] <= rm[3]);
    if (!__all(noimp)) {   // rare: rescale
      for (int rg = 0; rg < 4; rg++) {
        float t = lmx[rg];
        for (int m = 1; m < 16; m <<= 1) t = fmaxf(t, __shfl_xor(t, m, 16));
        t = fmaxf(t, rm[rg]);
        float a = fexp2(rm[rg] - t);
        os[rg] *= a;
        Oacc[0][rg] *= a; Oacc[1][rg] *= a; Oacc[2][rg] *= a; Oacc[3][rg] *= a;
        rm[rg] = t;
      }
    }

    for (int nt = 0; nt < 4; nt++)
      for (int rg = 0; rg < 4; rg++) {
        float p = fexp2(mv[nt][rg] - rm[rg]);   // <= 1 guaranteed
        os[rg] += p;
        Pw[quad * 4 + rg][nt * 16 + l15] = (f16)p;
      }
    // no barrier: Pw is wave-private; lgkmcnt orders write->read

    for (int ks = 0; ks < 2; ks++) {
      half8 pa = *(const half8*)(&Pw[l15][ks * 32 + quad * 8]);
      for (int nt = 0; nt < 4; nt++) {
        half8 vbv = *(const half8*)(&Vts[nt * 16 + l15][ks * 32 + quad * 8]);
        Oacc[nt] = __builtin_amdgcn_mfma_f32_16x16x32_f16(pa, vbv, Oacc[nt], 0, 0, 0);
      }
    }
  }

  int b = bh / 12, h = bh - b * 12;
  for (int rg = 0; rg < 4; rg++) {
    float t = os[rg];
    for (int m = 1; m < 16; m <<= 1) t += __shfl_xor(t, m, 16);
    float inv = 1.f / t;
    int srow = i0 + wave * 16 + quad * 4 + rg;
    for (int nt = 0; nt < 4; nt++) {
      int d = nt * 16 + l15;
      attn[((size_t)(b * 2048 + srow)) * 768 + h * 64 + d] =
          (f16)(Oacc[nt][rg] * inv);
    }
  }
}

// ---------------------------------------------------------------------------
__global__ __launch_bounds__(256) void k_gemm_out(
    const f16* __restrict__ A, const f16* __restrict__ Bt,
    const float* __restrict__ bias, float* __restrict__ out) {
  __shared__ f16 As[128][72];
  __shared__ f16 Bs[128][72];
  int tid  = threadIdx.x;
  int wave = tid >> 6, lane = tid & 63;
  int quad = lane >> 4, l15 = lane & 15;
  int wm = wave >> 1, wn = wave & 1;
  int m0 = blockIdx.y * 128;
  int n0 = blockIdx.x * 128;

  float4_t acc[4][4] = {};
  int r  = tid >> 3;
  int c8 = (tid & 7) * 8;

  for (int k0 = 0; k0 < 768; k0 += 64) {
    for (int rr = 0; rr < 128; rr += 32) {
      *(uint4*)(&As[r + rr][c8]) =
          *(const uint4*)(A  + (size_t)(m0 + r + rr) * 768 + k0 + c8);
      *(uint4*)(&Bs[r + rr][c8]) =
          *(const uint4*)(Bt + (size_t)(n0 + r + rr) * 768 + k0 + c8);
    }
    __syncthreads();
    half8 af[4][2], bf[4][2];
    for (int mt = 0; mt < 4; mt++)
      for (int ks = 0; ks < 2; ks++)
        af[mt][ks] = *(const half8*)(&As[wm * 64 + mt * 16 + l15][ks * 32 + quad * 8]);
    for (int nt = 0; nt < 4; nt++)
      for (int ks = 0; ks < 2; ks++)
        bf[nt][ks] = *(const half8*)(&Bs[wn * 64 + nt * 16 + l15][ks * 32 + quad * 8]);
    for (int ks = 0; ks < 2; ks++)
      for (int mt = 0; mt < 4; mt++)
        for (int nt = 0; nt < 4; nt++)
          acc[mt][nt] = __builtin_amdgcn_mfma_f32_16x16x32_f16(af[mt][ks], bf[nt][ks],
                                                               acc[mt][nt], 0, 0, 0);
    __syncthreads();
  }

  for (int mt = 0; mt < 4; mt++)
    for (int nt = 0; nt < 4; nt++)
      for (int rg = 0; rg < 4; rg++) {
        int R = m0 + wm * 64 + mt * 16 + quad * 4 + rg;
        int n = n0 + wn * 64 + nt * 16 + l15;
        out[(size_t)R * 768 + n] = acc[mt][nt][rg] + bias[n];
      }
}

// ---------------------------------------------------------------------------
extern "C" void kernel_launch(void* const* d_in, const int* in_sizes, int n_in,
                              void* d_out, int out_size, void* d_ws, size_t ws_size,
                              hipStream_t stream) {
  const float* x     = (const float*)d_in[0];
  const float* Wqkv  = (const float*)d_in[1];
  const float* bqkv  = (const float*)d_in[2];
  const float* Wout  = (const float*)d_in[3];
  const float* bout  = (const float*)d_in[4];
  float* out = (float*)d_out;

  char* ws = (char*)d_ws;
  size_t off = 0;
  f16* xh     = (f16*)(ws + off);
  off += (size_t)M1_ * HID_ * 2;
  f16* wqkvt  = (f16*)(ws + off); off += (size_t)N1_ * HID_ * 2;
  f16* woutt  = (f16*)(ws + off); off += (size_t)HID_ * HID_ * 2;
  f16* Qh     = (f16*)(ws + off); off += (size_t)BH_ * S_ * D_ * 2;
  f16* Kh     = (f16*)(ws + off); off += (size_t)BH_ * S_ * D_ * 2;
  f16* Vt     = (f16*)(ws + off); off += (size_t)BH_ * S_ * D_ * 2;
  float* qq   = (float*)(ws + off); off += (size_t)BH_ * S_ * 4;
  float* kk   = (float*)(ws + off); off += (size_t)BH_ * S_ * 4;
  float* lognc= (float*)(ws + off); off += (size_t)BH_ * S_ * 4;
  f16* attn   = xh;  // xh dead after k_gemm_qkv

  k_convert_x<<<dim3(M1_ * HID_ / 4 / 256), dim3(256), 0, stream>>>(x, xh);
  k_transpose_w<<<dim3(9, 768), dim3(256), 0, stream>>>(Wqkv, wqkvt, N1_, HID_);
  k_transpose_w<<<dim3(3, 768), dim3(256), 0, stream>>>(Wout, woutt, HID_, HID_);

  k_gemm_qkv<<<dim3(N1_ / 128, M1_ / 128), dim3(256), 0, stream>>>(
      xh, wqkvt, bqkv, Qh, Kh, Vt);

  k_norms<<<dim3(BH_ * S_ / 256), dim3(256), 0, stream>>>(Qh, Kh, qq, kk);

  k_colsum<<<dim3(S_ / 64, BH_), dim3(256), 0, stream>>>(Qh, Kh, qq, kk, lognc);

  k_flash<<<dim3(S_ / 64, BH_), dim3(256), 0, stream>>>(
      Qh, Kh, Vt, qq, kk, lognc, attn);

  k_gemm_out<<<dim3(HID_ / 128, M1_ / 128), dim3(256), 0, stream>>>(
      attn, woutt, bout, out);
}

// Round 10
// 474.996 us; speedup vs baseline: 1.0353x; 1.0180x over previous
//
#include <hip/hip_runtime.h>
#include <cstdint>
#include <cstddef>

// Problem constants
#define B_   4
#define S_   2048
#define HID_ 768
#define H_   12
#define D_   64
#define BH_  (B_*H_)        // 48
#define M1_  (B_*S_)        // 8192
#define N1_  (3*HID_)       // 2304
#define PWR  65.5f          // D + alpha

typedef _Float16 f16;
using half8    = __attribute__((ext_vector_type(8))) _Float16;
using float4_t = __attribute__((ext_vector_type(4))) float;

__device__ __forceinline__ float fexp2(float x) { return __builtin_amdgcn_exp2f(x); }
__device__ __forceinline__ float flog2(float x) { return __builtin_amdgcn_logf(x); }
__device__ __forceinline__ float fsqrt(float x) { return __builtin_amdgcn_sqrtf(x); }

// ---------------------------------------------------------------------------
__global__ __launch_bounds__(256) void k_convert_x(const float* __restrict__ x,
                                                   f16* __restrict__ xh) {
  int i = blockIdx.x * 256 + threadIdx.x;
  const float4* xv = (const float4*)x;
  float4 v = xv[i];
  f16 tmp[4] = {(f16)v.x, (f16)v.y, (f16)v.z, (f16)v.w};
  *(uint2*)(xh + 4 * (size_t)i) = *(uint2*)tmp;
}

__global__ __launch_bounds__(256) void k_transpose_w(const float* __restrict__ w,
                                                     f16* __restrict__ wt,
                                                     int N, int K) {
  int n = blockIdx.x * 256 + threadIdx.x;
  int k = blockIdx.y;
  if (n < N) wt[(size_t)n * K + k] = (f16)w[(size_t)k * N + n];
}

// ---------------------------------------------------------------------------
__global__ __launch_bounds__(256) void k_gemm_qkv(
    const f16* __restrict__ A, const f16* __restrict__ Bt,
    const float* __restrict__ bias,
    f16* __restrict__ Qh, f16* __restrict__ Kh, f16* __restrict__ Vt) {
  __shared__ f16 As[128][72];
  __shared__ f16 Bs[128][72];
  int tid  = threadIdx.x;
  int wave = tid >> 6, lane = tid & 63;
  int quad = lane >> 4, l15 = lane & 15;
  int wm = wave >> 1, wn = wave & 1;
  int m0 = blockIdx.y * 128;
  int n0 = blockIdx.x * 128;

  float4_t acc[4][4] = {};
  int r  = tid >> 3;
  int c8 = (tid & 7) * 8;

  for (int k0 = 0; k0 < 768; k0 += 64) {
    for (int rr = 0; rr < 128; rr += 32) {
      *(uint4*)(&As[r + rr][c8]) =
          *(const uint4*)(A  + (size_t)(m0 + r + rr) * 768 + k0 + c8);
      *(uint4*)(&Bs[r + rr][c8]) =
          *(const uint4*)(Bt + (size_t)(n0 + r + rr) * 768 + k0 + c8);
    }
    __syncthreads();
    half8 af[4][2], bf[4][2];
    for (int mt = 0; mt < 4; mt++)
      for (int ks = 0; ks < 2; ks++)
        af[mt][ks] = *(const half8*)(&As[wm * 64 + mt * 16 + l15][ks * 32 + quad * 8]);
    for (int nt = 0; nt < 4; nt++)
      for (int ks = 0; ks < 2; ks++)
        bf[nt][ks] = *(const half8*)(&Bs[wn * 64 + nt * 16 + l15][ks * 32 + quad * 8]);
    for (int ks = 0; ks < 2; ks++)
      for (int mt = 0; mt < 4; mt++)
        for (int nt = 0; nt < 4; nt++)
          acc[mt][nt] = __builtin_amdgcn_mfma_f32_16x16x32_f16(af[mt][ks], bf[nt][ks],
                                                               acc[mt][nt], 0, 0, 0);
    __syncthreads();
  }

  for (int mt = 0; mt < 4; mt++)
    for (int nt = 0; nt < 4; nt++)
      for (int rg = 0; rg < 4; rg++) {
        int R = m0 + wm * 64 + mt * 16 + quad * 4 + rg;
        int n = n0 + wn * 64 + nt * 16 + l15;
        float v = acc[mt][nt][rg] + bias[n];
        int b = R >> 11, s = R & 2047;
        int which = n / 768;
        int rem = n - which * 768;
        int h = rem >> 6, d = rem & 63;
        int bh = b * 12 + h;
        f16 hv = (f16)v;
        if (which == 0)      Qh[((size_t)bh * 2048 + s) * 64 + d] = hv;
        else if (which == 1) Kh[((size_t)bh * 2048 + s) * 64 + d] = hv;
        else                 Vt[((size_t)bh * 64 + d) * 2048 + s] = hv;
      }
}

// ---------------------------------------------------------------------------
__global__ __launch_bounds__(256) void k_norms(const f16* __restrict__ Qh,
                                               const f16* __restrict__ Kh,
                                               float* __restrict__ qq,
                                               float* __restrict__ kk) {
  int i = blockIdx.x * 256 + threadIdx.x;
  if (i >= BH_ * S_) return;
  const f16* p = Qh + (size_t)i * 64;
  float s1 = 0.f, s2 = 0.f;
  for (int d = 0; d < 64; d += 8) {
    half8 v = *(const half8*)(p + d);
    for (int j = 0; j < 8; j++) { float t = (float)v[j]; s1 += t * t; }
  }
  p = Kh + (size_t)i * 64;
  for (int d = 0; d < 64; d += 8) {
    half8 v = *(const half8*)(p + d);
    for (int j = 0; j < 8; j++) { float t = (float)v[j]; s2 += t * t; }
  }
  qq[i] = s1;
  kk[i] = s2;
}

// ---------------------------------------------------------------------------
// Pass 1: column logsumexp. 64-col j-tile (K resident), Q streamed via LDS.
// Lazy online max via running min-d2. 18.9 KB LDS -> high occupancy.
__global__ __launch_bounds__(256, 6) void k_colsum(
    const f16* __restrict__ Qh, const f16* __restrict__ Kh,
    const float* __restrict__ qq, const float* __restrict__ kk,
    float* __restrict__ lognc) {
  int bh = blockIdx.y;
  int j0 = blockIdx.x * 64;
  __shared__ __align__(16) char smem[18944];
  f16 (*Kt)[72] = (f16(*)[72])smem;            // [64][72] resident
  f16 (*Qt)[72] = (f16(*)[72])(smem + 9216);   // [64][72] streamed
  float* kks = (float*)(smem + 18432);         // [64]
  float* qqs = kks + 64;                       // [64]

  int tid = threadIdx.x;
  int wave = tid >> 6, lane = tid & 63, quad = lane >> 4, l15 = lane & 15;
  int r = tid >> 3, c8 = (tid & 7) * 8;
  const f16* Kb = Kh + (size_t)bh * 2048 * 64;
  const f16* Qb = Qh + (size_t)bh * 2048 * 64;

  for (int rr = 0; rr < 64; rr += 32)
    *(uint4*)(&Kt[r + rr][c8]) = *(const uint4*)(Kb + (size_t)(j0 + r + rr) * 64 + c8);
  if (tid < 64) kks[tid] = kk[bh * 2048 + j0 + tid];
  __syncthreads();

  half8 af[2];
  for (int ks = 0; ks < 2; ks++)
    af[ks] = *(const half8*)(&Kt[wave * 16 + l15][ks * 32 + quad * 8]);
  float kkv[4];
  for (int t = 0; t < 4; t++) kkv[t] = kks[wave * 16 + quad * 4 + t];

  float rm[4], rmind2[4], rs[4];
  for (int t = 0; t < 4; t++) { rm[t] = -1e30f; rmind2[t] = 1e30f; rs[t] = 0.f; }

  for (int it = 0; it < 32; it++) {
    __syncthreads();
    int i0 = it * 64;
    for (int rr = 0; rr < 64; rr += 32)
      *(uint4*)(&Qt[r + rr][c8]) = *(const uint4*)(Qb + (size_t)(i0 + r + rr) * 64 + c8);
    if (tid < 64) qqs[tid] = qq[bh * 2048 + i0 + tid];
    __syncthreads();

    float4_t acc[4] = {};
    for (int nt = 0; nt < 4; nt++)
      for (int ks = 0; ks < 2; ks++) {
        half8 bfv = *(const half8*)(&Qt[nt * 16 + l15][ks * 32 + quad * 8]);
        acc[nt] = __builtin_amdgcn_mfma_f32_16x16x32_f16(af[ks], bfv, acc[nt], 0, 0, 0);
      }

    float d2v[4][4];
    float lmn[4] = {1e30f, 1e30f, 1e30f, 1e30f};
    for (int nt = 0; nt < 4; nt++) {
      float qn = qqs[nt * 16 + l15];
      for (int rg = 0; rg < 4; rg++) {
        float d2 = fmaxf(fmaf(-2.f, acc[nt][rg], kkv[rg] + qn), 0.f);
        d2v[nt][rg] = d2;
        lmn[rg] = fminf(lmn[rg], d2);
      }
    }
    bool noimp = (lmn[0] >= rmind2[0]) & (lmn[1] >= rmind2[1]) &
                 (lmn[2] >= rmind2[2]) & (lmn[3] >= rmind2[3]);
    if (!__all(noimp)) {
      for (int rg = 0; rg < 4; rg++) {
        float t = lmn[rg];
        for (int m = 1; m < 16; m <<= 1) t = fminf(t, __shfl_xor(t, m, 16));
        t = fminf(t, rmind2[rg]);
        float nm = -PWR * flog2(1.f + fsqrt(t));
        rs[rg] *= fexp2(rm[rg] - nm);
        rm[rg] = nm; rmind2[rg] = t;
      }
    }
    for (int nt = 0; nt < 4; nt++)
      for (int rg = 0; rg < 4; rg++) {
        float g = fsqrt(d2v[nt][rg]);
        rs[rg] += fexp2(fmaf(-PWR, flog2(1.f + g), -rm[rg]));
      }
  }
  for (int rg = 0; rg < 4; rg++) {
    float s = rs[rg];
    for (int m = 1; m < 16; m <<= 1) s += __shfl_xor(s, m, 16);
    if (l15 == 0) {
      int j = j0 + wave * 16 + quad * 4 + rg;
      lognc[bh * 2048 + j] = rm[rg] + flog2(s);
    }
  }
}

// ---------------------------------------------------------------------------
// Pass 2: flash, 64-row i-tile. Qt overlays Kt (Qt dead after frag load).
// Wave-private P tile (no barrier). 28.4 KB LDS -> 5 blocks/CU.
__global__ __launch_bounds__(256, 5) void k_flash(
    const f16* __restrict__ Qh, const f16* __restrict__ Kh, const f16* __restrict__ Vt,
    const float* __restrict__ qq, const float* __restrict__ kk,
    const float* __restrict__ lognc, f16* __restrict__ attn) {
  int bh = blockIdx.y;
  int i0 = blockIdx.x * 64;
  __shared__ __align__(16) char smem[28416];
  f16 (*Qt)[72]  = (f16(*)[72])smem;            // [64][72], start only
  f16 (*Kt)[72]  = (f16(*)[72])smem;            // [64][72] per iter (overlay)
  f16 (*Vts)[72] = (f16(*)[72])(smem + 9216);   // [64][72] per iter
  f16 (*PldsAll)[72] = (f16(*)[72])(smem + 18432);  // [64][72]: 16 rows/wave
  float* qqs = (float*)(smem + 27648);          // [64]
  float* kks = qqs + 64;                        // [64]
  float* lns = kks + 64;                        // [64]

  int tid = threadIdx.x;
  int wave = tid >> 6, lane = tid & 63, quad = lane >> 4, l15 = lane & 15;
  int r = tid >> 3, c8 = (tid & 7) * 8;
  f16 (*Pw)[72] = PldsAll + wave * 16;
  const f16* Qb = Qh + (size_t)bh * 2048 * 64;
  const f16* Kb = Kh + (size_t)bh * 2048 * 64;
  const f16* Vb = Vt + (size_t)bh * 64 * 2048;

  for (int rr = 0; rr < 64; rr += 32)
    *(uint4*)(&Qt[r + rr][c8]) = *(const uint4*)(Qb + (size_t)(i0 + r + rr) * 64 + c8);
  if (tid < 64) qqs[tid] = qq[bh * 2048 + i0 + tid];
  __syncthreads();

  half8 af[2];
  for (int ks = 0; ks < 2; ks++)
    af[ks] = *(const half8*)(&Qt[wave * 16 + l15][ks * 32 + quad * 8]);
  float qv[4];
  for (int t = 0; t < 4; t++) qv[t] = qqs[wave * 16 + quad * 4 + t];

  float rm[4], os[4];
  float4_t Oacc[4] = {};
  for (int t = 0; t < 4; t++) { rm[t] = -1e30f; os[t] = 0.f; }

  for (int jt = 0; jt < 32; jt++) {
    __syncthreads();   // prev compute done (incl. pre-loop Qt frag reads)
    int j0 = jt * 64;
    for (int rr = 0; rr < 64; rr += 32) {
      *(uint4*)(&Kt[r + rr][c8]) =
          *(const uint4*)(Kb + (size_t)(j0 + r + rr) * 64 + c8);
      *(uint4*)(&Vts[r + rr][c8]) =
          *(const uint4*)(Vb + (size_t)(r + rr) * 2048 + j0 + c8);
    }
    if (tid < 64) {
      kks[tid] = kk[bh * 2048 + j0 + tid];
      lns[tid] = -0.5f * lognc[bh * 2048 + j0 + tid];
    }
    __syncthreads();

    float4_t acc[4] = {};
    for (int nt = 0; nt < 4; nt++)
      for (int ks = 0; ks < 2; ks++) {
        half8 bfv = *(const half8*)(&Kt[nt * 16 + l15][ks * 32 + quad * 8]);
        acc[nt] = __builtin_amdgcn_mfma_f32_16x16x32_f16(af[ks], bfv, acc[nt], 0, 0, 0);
      }

    float mv[4][4];
    float lmx[4] = {-1e30f, -1e30f, -1e30f, -1e30f};
    for (int nt = 0; nt < 4; nt++) {
      float kn = kks[nt * 16 + l15];
      float bias = lns[nt * 16 + l15];
      for (int rg = 0; rg < 4; rg++) {
        float d2 = fmaxf(fmaf(-2.f, acc[nt][rg], qv[rg] + kn), 0.f);
        float g = fsqrt(d2);
        float m = fmaf(-PWR, flog2(1.f + g), bias);
        mv[nt][rg] = m;
        lmx[rg] = fmaxf(lmx[rg], m);
      }
    }
    bool noimp = (lmx[0] <= rm[0]) & (lmx[1] <= rm[1]) &
                 (lmx[2] <= rm[2]) & (lmx[3] <= rm[3]);
    if (!__all(noimp)) {   // rare: rescale
      for (int rg = 0; rg < 4; rg++) {
        float t = lmx[rg];
        for (int m = 1; m < 16; m <<= 1) t = fmaxf(t, __shfl_xor(t, m, 16));
        t = fmaxf(t, rm[rg]);
        float a = fexp2(rm[rg] - t);
        os[rg] *= a;
        Oacc[0][rg] *= a; Oacc[1][rg] *= a; Oacc[2][rg] *= a; Oacc[3][rg] *= a;
        rm[rg] = t;
      }
    }

    for (int nt = 0; nt < 4; nt++)
      for (int rg = 0; rg < 4; rg++) {
        float p = fexp2(mv[nt][rg] - rm[rg]);   // <= 1 guaranteed
        os[rg] += p;
        Pw[quad * 4 + rg][nt * 16 + l15] = (f16)p;
      }
    // no barrier: Pw is wave-private; lgkmcnt orders write->read

    for (int ks = 0; ks < 2; ks++) {
      half8 pa = *(const half8*)(&Pw[l15][ks * 32 + quad * 8]);
      for (int nt = 0; nt < 4; nt++) {
        half8 vbv = *(const half8*)(&Vts[nt * 16 + l15][ks * 32 + quad * 8]);
        Oacc[nt] = __builtin_amdgcn_mfma_f32_16x16x32_f16(pa, vbv, Oacc[nt], 0, 0, 0);
      }
    }
  }

  int b = bh / 12, h = bh - b * 12;
  for (int rg = 0; rg < 4; rg++) {
    float t = os[rg];
    for (int m = 1; m < 16; m <<= 1) t += __shfl_xor(t, m, 16);
    float inv = 1.f / t;
    int srow = i0 + wave * 16 + quad * 4 + rg;
    for (int nt = 0; nt < 4; nt++) {
      int d = nt * 16 + l15;
      attn[((size_t)(b * 2048 + srow)) * 768 + h * 64 + d] =
          (f16)(Oacc[nt][rg] * inv);
    }
  }
}

// ---------------------------------------------------------------------------
__global__ __launch_bounds__(256) void k_gemm_out(
    const f16* __restrict__ A, const f16* __restrict__ Bt,
    const float* __restrict__ bias, float* __restrict__ out) {
  __shared__ f16 As[128][72];
  __shared__ f16 Bs[128][72];
  int tid  = threadIdx.x;
  int wave = tid >> 6, lane = tid & 63;
  int quad = lane >> 4, l15 = lane & 15;
  int wm = wave >> 1, wn = wave & 1;
  int m0 = blockIdx.y * 128;
  int n0 = blockIdx.x * 128;

  float4_t acc[4][4] = {};
  int r  = tid >> 3;
  int c8 = (tid & 7) * 8;

  for (int k0 = 0; k0 < 768; k0 += 64) {
    for (int rr = 0; rr < 128; rr += 32) {
      *(uint4*)(&As[r + rr][c8]) =
          *(const uint4*)(A  + (size_t)(m0 + r + rr) * 768 + k0 + c8);
      *(uint4*)(&Bs[r + rr][c8]) =
          *(const uint4*)(Bt + (size_t)(n0 + r + rr) * 768 + k0 + c8);
    }
    __syncthreads();
    half8 af[4][2], bf[4][2];
    for (int mt = 0; mt < 4; mt++)
      for (int ks = 0; ks < 2; ks++)
        af[mt][ks] = *(const half8*)(&As[wm * 64 + mt * 16 + l15][ks * 32 + quad * 8]);
    for (int nt = 0; nt < 4; nt++)
      for (int ks = 0; ks < 2; ks++)
        bf[nt][ks] = *(const half8*)(&Bs[wn * 64 + nt * 16 + l15][ks * 32 + quad * 8]);
    for (int ks = 0; ks < 2; ks++)
      for (int mt = 0; mt < 4; mt++)
        for (int nt = 0; nt < 4; nt++)
          acc[mt][nt] = __builtin_amdgcn_mfma_f32_16x16x32_f16(af[mt][ks], bf[nt][ks],
                                                               acc[mt][nt], 0, 0, 0);
    __syncthreads();
  }

  for (int mt = 0; mt < 4; mt++)
    for (int nt = 0; nt < 4; nt++)
      for (int rg = 0; rg < 4; rg++) {
        int R = m0 + wm * 64 + mt * 16 + quad * 4 + rg;
        int n = n0 + wn * 64 + nt * 16 + l15;
        out[(size_t)R * 768 + n] = acc[mt][nt][rg] + bias[n];
      }
}

// ---------------------------------------------------------------------------
extern "C" void kernel_launch(void* const* d_in, const int* in_sizes, int n_in,
                              void* d_out, int out_size, void* d_ws, size_t ws_size,
                              hipStream_t stream) {
  const float* x     = (const float*)d_in[0];
  const float* Wqkv  = (const float*)d_in[1];
  const float* bqkv  = (const float*)d_in[2];
  const float* Wout  = (const float*)d_in[3];
  const float* bout  = (const float*)d_in[4];
  float* out = (float*)d_out;

  char* ws = (char*)d_ws;
  size_t off = 0;
  f16* xh     = (f16*)(ws + off);
  off += (size_t)M1_ * HID_ * 2;
  f16* wqkvt  = (f16*)(ws + off); off += (size_t)N1_ * HID_ * 2;
  f16* woutt  = (f16*)(ws + off); off += (size_t)HID_ * HID_ * 2;
  f16* Qh     = (f16*)(ws + off); off += (size_t)BH_ * S_ * D_ * 2;
  f16* Kh     = (f16*)(ws + off); off += (size_t)BH_ * S_ * D_ * 2;
  f16* Vt     = (f16*)(ws + off); off += (size_t)BH_ * S_ * D_ * 2;
  float* qq   = (float*)(ws + off); off += (size_t)BH_ * S_ * 4;
  float* kk   = (float*)(ws + off); off += (size_t)BH_ * S_ * 4;
  float* lognc= (float*)(ws + off); off += (size_t)BH_ * S_ * 4;
  f16* attn   = xh;  // xh dead after k_gemm_qkv

  k_convert_x<<<dim3(M1_ * HID_ / 4 / 256), dim3(256), 0, stream>>>(x, xh);
  k_transpose_w<<<dim3(9, 768), dim3(256), 0, stream>>>(Wqkv, wqkvt, N1_, HID_);
  k_transpose_w<<<dim3(3, 768), dim3(256), 0, stream>>>(Wout, woutt, HID_, HID_);

  k_gemm_qkv<<<dim3(N1_ / 128, M1_ / 128), dim3(256), 0, stream>>>(
      xh, wqkvt, bqkv, Qh, Kh, Vt);

  k_norms<<<dim3(BH_ * S_ / 256), dim3(256), 0, stream>>>(Qh, Kh, qq, kk);

  k_colsum<<<dim3(S_ / 64, BH_), dim3(256), 0, stream>>>(Qh, Kh, qq, kk, lognc);

  k_flash<<<dim3(S_ / 64, BH_), dim3(256), 0, stream>>>(
      Qh, Kh, Vt, qq, kk, lognc, attn);

  k_gemm_out<<<dim3(HID_ / 128, M1_ / 128), dim3(256), 0, stream>>>(
      attn, woutt, bout, out);
}

// Round 11
// 456.778 us; speedup vs baseline: 1.0766x; 1.0399x over previous
//
#include <hip/hip_runtime.h>
#include <cstdint>
#include <cstddef>

// Problem constants
#define B_   4
#define S_   2048
#define HID_ 768
#define H_   12
#define D_   64
#define BH_  (B_*H_)        // 48
#define M1_  (B_*S_)        // 8192
#define N1_  (3*HID_)       // 2304
#define PWR  65.5f          // D + alpha

typedef _Float16 f16;
using half8    = __attribute__((ext_vector_type(8))) _Float16;
using float4_t = __attribute__((ext_vector_type(4))) float;

__device__ __forceinline__ float fexp2(float x) { return __builtin_amdgcn_exp2f(x); }
__device__ __forceinline__ float flog2(float x) { return __builtin_amdgcn_logf(x); }
__device__ __forceinline__ float fsqrt(float x) { return __builtin_amdgcn_sqrtf(x); }

// Direct global->LDS DMA, 16B per lane. LDS dest = uniform base + lane*16.
#define AS1 __attribute__((address_space(1)))
#define AS3 __attribute__((address_space(3)))
__device__ __forceinline__ void gl_lds16(const f16* g, f16* l) {
  __builtin_amdgcn_global_load_lds((const AS1 void*)g, (AS3 void*)l, 16, 0, 0);
}

// ---------------------------------------------------------------------------
__global__ __launch_bounds__(256) void k_convert_x(const float* __restrict__ x,
                                                   f16* __restrict__ xh) {
  int i = blockIdx.x * 256 + threadIdx.x;
  const float4* xv = (const float4*)x;
  float4 v = xv[i];
  f16 tmp[4] = {(f16)v.x, (f16)v.y, (f16)v.z, (f16)v.w};
  *(uint2*)(xh + 4 * (size_t)i) = *(uint2*)tmp;
}

__global__ __launch_bounds__(256) void k_transpose_w(const float* __restrict__ w,
                                                     f16* __restrict__ wt,
                                                     int N, int K) {
  int n = blockIdx.x * 256 + threadIdx.x;
  int k = blockIdx.y;
  if (n < N) wt[(size_t)n * K + k] = (f16)w[(size_t)k * N + n];
}

// ---------------------------------------------------------------------------
__global__ __launch_bounds__(256) void k_gemm_qkv(
    const f16* __restrict__ A, const f16* __restrict__ Bt,
    const float* __restrict__ bias,
    f16* __restrict__ Qh, f16* __restrict__ Kh, f16* __restrict__ Vt) {
  __shared__ f16 As[128][72];
  __shared__ f16 Bs[128][72];
  int tid  = threadIdx.x;
  int wave = tid >> 6, lane = tid & 63;
  int quad = lane >> 4, l15 = lane & 15;
  int wm = wave >> 1, wn = wave & 1;
  int m0 = blockIdx.y * 128;
  int n0 = blockIdx.x * 128;

  float4_t acc[4][4] = {};
  int r  = tid >> 3;
  int c8 = (tid & 7) * 8;

  for (int k0 = 0; k0 < 768; k0 += 64) {
    for (int rr = 0; rr < 128; rr += 32) {
      *(uint4*)(&As[r + rr][c8]) =
          *(const uint4*)(A  + (size_t)(m0 + r + rr) * 768 + k0 + c8);
      *(uint4*)(&Bs[r + rr][c8]) =
          *(const uint4*)(Bt + (size_t)(n0 + r + rr) * 768 + k0 + c8);
    }
    __syncthreads();
    half8 af[4][2], bf[4][2];
    for (int mt = 0; mt < 4; mt++)
      for (int ks = 0; ks < 2; ks++)
        af[mt][ks] = *(const half8*)(&As[wm * 64 + mt * 16 + l15][ks * 32 + quad * 8]);
    for (int nt = 0; nt < 4; nt++)
      for (int ks = 0; ks < 2; ks++)
        bf[nt][ks] = *(const half8*)(&Bs[wn * 64 + nt * 16 + l15][ks * 32 + quad * 8]);
    for (int ks = 0; ks < 2; ks++)
      for (int mt = 0; mt < 4; mt++)
        for (int nt = 0; nt < 4; nt++)
          acc[mt][nt] = __builtin_amdgcn_mfma_f32_16x16x32_f16(af[mt][ks], bf[nt][ks],
                                                               acc[mt][nt], 0, 0, 0);
    __syncthreads();
  }

  for (int mt = 0; mt < 4; mt++)
    for (int nt = 0; nt < 4; nt++)
      for (int rg = 0; rg < 4; rg++) {
        int R = m0 + wm * 64 + mt * 16 + quad * 4 + rg;
        int n = n0 + wn * 64 + nt * 16 + l15;
        float v = acc[mt][nt][rg] + bias[n];
        int b = R >> 11, s = R & 2047;
        int which = n / 768;
        int rem = n - which * 768;
        int h = rem >> 6, d = rem & 63;
        int bh = b * 12 + h;
        f16 hv = (f16)v;
        if (which == 0)      Qh[((size_t)bh * 2048 + s) * 64 + d] = hv;
        else if (which == 1) Kh[((size_t)bh * 2048 + s) * 64 + d] = hv;
        else                 Vt[((size_t)bh * 64 + d) * 2048 + s] = hv;
      }
}

// ---------------------------------------------------------------------------
__global__ __launch_bounds__(256) void k_norms(const f16* __restrict__ Qh,
                                               const f16* __restrict__ Kh,
                                               float* __restrict__ qq,
                                               float* __restrict__ kk) {
  int i = blockIdx.x * 256 + threadIdx.x;
  if (i >= BH_ * S_) return;
  const f16* p = Qh + (size_t)i * 64;
  float s1 = 0.f, s2 = 0.f;
  for (int d = 0; d < 64; d += 8) {
    half8 v = *(const half8*)(p + d);
    for (int j = 0; j < 8; j++) { float t = (float)v[j]; s1 += t * t; }
  }
  p = Kh + (size_t)i * 64;
  for (int d = 0; d < 64; d += 8) {
    half8 v = *(const half8*)(p + d);
    for (int j = 0; j < 8; j++) { float t = (float)v[j]; s2 += t * t; }
  }
  qq[i] = s1;
  kk[i] = s2;
}

// ---------------------------------------------------------------------------
// Swizzled unpadded LDS tiles [64][64] f16: logical 8-f16 group g of row r is
// stored at physical group g ^ (r&7). Staged by global_load_lds (source addr
// carries the swizzle; LDS dest is the mandated uniform-base + lane*16).
// Frag reads: addr = row*64 + ((ks*4+quad) ^ (l15&7))*8 -> 2 lanes/bank (free).

// Pass 1: column logsumexp. K resident, Q streamed. Lazy online max (min-d2).
__global__ __launch_bounds__(256, 6) void k_colsum(
    const f16* __restrict__ Qh, const f16* __restrict__ Kh,
    const float* __restrict__ qq, const float* __restrict__ kk,
    float* __restrict__ lognc) {
  int bh = blockIdx.y;
  int j0 = blockIdx.x * 64;
  __shared__ __align__(16) char smem[16896];
  f16* KtB = (f16*)smem;               // [64][64] swizzled, resident
  f16* QtB = (f16*)(smem + 8192);      // [64][64] swizzled, streamed
  float* kks = (float*)(smem + 16384); // [64]
  float* qqs = kks + 64;               // [64]

  int tid = threadIdx.x;
  int wave = tid >> 6, lane = tid & 63, quad = lane >> 4, l15 = lane & 15;
  int rloc = lane >> 3, cg = lane & 7;
  int colOff = (cg ^ rloc) * 8;        // swizzled source column (f16 units)
  const f16* Kb = Kh + (size_t)bh * 2048 * 64;
  const f16* Qb = Qh + (size_t)bh * 2048 * 64;

  // stage K (2 DMA calls/wave: rows wave*8+rloc, +32)
  gl_lds16(Kb + (size_t)(j0 + wave * 8 + rloc) * 64 + colOff,
           KtB + (wave * 8) * 64);
  gl_lds16(Kb + (size_t)(j0 + 32 + wave * 8 + rloc) * 64 + colOff,
           KtB + (32 + wave * 8) * 64);
  if (tid < 64) kks[tid] = kk[bh * 2048 + j0 + tid];
  __syncthreads();

  int swq = (l15 & 7);
  half8 af[2];
  for (int ks = 0; ks < 2; ks++)
    af[ks] = *(const half8*)(KtB + (size_t)(wave * 16 + l15) * 64 +
                             (((ks * 4 + quad) ^ swq) * 8));
  float kkv[4];
  for (int t = 0; t < 4; t++) kkv[t] = kks[wave * 16 + quad * 4 + t];

  float rm[4], rmind2[4], rs[4];
  for (int t = 0; t < 4; t++) { rm[t] = -1e30f; rmind2[t] = 1e30f; rs[t] = 0.f; }

  const f16* sq0 = Qb + (size_t)(wave * 8 + rloc) * 64 + colOff;
  const f16* sq1 = Qb + (size_t)(32 + wave * 8 + rloc) * 64 + colOff;

  for (int it = 0; it < 32; it++) {
    __syncthreads();
    gl_lds16(sq0, QtB + (wave * 8) * 64);
    gl_lds16(sq1, QtB + (32 + wave * 8) * 64);
    sq0 += 64 * 64; sq1 += 64 * 64;
    if (tid < 64) qqs[tid] = qq[bh * 2048 + it * 64 + tid];
    __syncthreads();

    float4_t acc[4] = {};
    for (int nt = 0; nt < 4; nt++)
      for (int ks = 0; ks < 2; ks++) {
        half8 bfv = *(const half8*)(QtB + (size_t)(nt * 16 + l15) * 64 +
                                    (((ks * 4 + quad) ^ swq) * 8));
        acc[nt] = __builtin_amdgcn_mfma_f32_16x16x32_f16(af[ks], bfv, acc[nt], 0, 0, 0);
      }

    float d2v[4][4];
    float lmn[4] = {1e30f, 1e30f, 1e30f, 1e30f};
    for (int nt = 0; nt < 4; nt++) {
      float qn = qqs[nt * 16 + l15];
      for (int rg = 0; rg < 4; rg++) {
        float d2 = fmaxf(fmaf(-2.f, acc[nt][rg], kkv[rg] + qn), 0.f);
        d2v[nt][rg] = d2;
        lmn[rg] = fminf(lmn[rg], d2);
      }
    }
    bool noimp = (lmn[0] >= rmind2[0]) & (lmn[1] >= rmind2[1]) &
                 (lmn[2] >= rmind2[2]) & (lmn[3] >= rmind2[3]);
    if (!__all(noimp)) {
      for (int rg = 0; rg < 4; rg++) {
        float t = lmn[rg];
        for (int m = 1; m < 16; m <<= 1) t = fminf(t, __shfl_xor(t, m, 16));
        t = fminf(t, rmind2[rg]);
        float nm = -PWR * flog2(1.f + fsqrt(t));
        rs[rg] *= fexp2(rm[rg] - nm);
        rm[rg] = nm; rmind2[rg] = t;
      }
    }
    for (int nt = 0; nt < 4; nt++)
      for (int rg = 0; rg < 4; rg++) {
        float g = fsqrt(d2v[nt][rg]);
        rs[rg] += fexp2(fmaf(-PWR, flog2(1.f + g), -rm[rg]));
      }
  }
  for (int rg = 0; rg < 4; rg++) {
    float s = rs[rg];
    for (int m = 1; m < 16; m <<= 1) s += __shfl_xor(s, m, 16);
    if (l15 == 0) {
      int j = j0 + wave * 16 + quad * 4 + rg;
      lognc[bh * 2048 + j] = rm[rg] + flog2(s);
    }
  }
}

// ---------------------------------------------------------------------------
// Pass 2: flash. Q staged into KtB region (dead after frag load). K/V DMA'd
// per iter. Wave-private P tile (no barrier). Lazy online max.
__global__ __launch_bounds__(256, 4) void k_flash(
    const f16* __restrict__ Qh, const f16* __restrict__ Kh, const f16* __restrict__ Vt,
    const float* __restrict__ qq, const float* __restrict__ kk,
    const float* __restrict__ lognc, f16* __restrict__ attn) {
  int bh = blockIdx.y;
  int i0 = blockIdx.x * 64;
  __shared__ __align__(16) char smem[26368];
  f16* KtB = (f16*)smem;                         // [64][64] swizzled (Q then K)
  f16* VtB = (f16*)(smem + 8192);                // [64][64] swizzled [d][j]
  f16 (*PldsAll)[72] = (f16(*)[72])(smem + 16384);  // [64][72], 16 rows/wave
  float* qqs = (float*)(smem + 25600);           // [64]
  float* kks = qqs + 64;                         // [64]
  float* lns = kks + 64;                         // [64]

  int tid = threadIdx.x;
  int wave = tid >> 6, lane = tid & 63, quad = lane >> 4, l15 = lane & 15;
  int rloc = lane >> 3, cg = lane & 7;
  int colOff = (cg ^ rloc) * 8;
  f16 (*Pw)[72] = PldsAll + wave * 16;
  const f16* Qb = Qh + (size_t)bh * 2048 * 64;
  const f16* Kb = Kh + (size_t)bh * 2048 * 64;
  const f16* Vb = Vt + (size_t)bh * 64 * 2048;

  // stage Q into KtB
  gl_lds16(Qb + (size_t)(i0 + wave * 8 + rloc) * 64 + colOff,
           KtB + (wave * 8) * 64);
  gl_lds16(Qb + (size_t)(i0 + 32 + wave * 8 + rloc) * 64 + colOff,
           KtB + (32 + wave * 8) * 64);
  if (tid < 64) qqs[tid] = qq[bh * 2048 + i0 + tid];
  __syncthreads();

  int swq = (l15 & 7);
  half8 af[2];
  for (int ks = 0; ks < 2; ks++)
    af[ks] = *(const half8*)(KtB + (size_t)(wave * 16 + l15) * 64 +
                             (((ks * 4 + quad) ^ swq) * 8));
  float qv[4];
  for (int t = 0; t < 4; t++) qv[t] = qqs[wave * 16 + quad * 4 + t];

  float rm[4], os[4];
  float4_t Oacc[4] = {};
  for (int t = 0; t < 4; t++) { rm[t] = -1e30f; os[t] = 0.f; }

  const f16* sk0 = Kb + (size_t)(wave * 8 + rloc) * 64 + colOff;
  const f16* sk1 = Kb + (size_t)(32 + wave * 8 + rloc) * 64 + colOff;
  const f16* sv0 = Vb + (size_t)(wave * 8 + rloc) * 2048 + colOff;
  const f16* sv1 = Vb + (size_t)(32 + wave * 8 + rloc) * 2048 + colOff;

  for (int jt = 0; jt < 32; jt++) {
    __syncthreads();   // prev reads of KtB/VtB done (Q frags read pre-loop)
    gl_lds16(sk0, KtB + (wave * 8) * 64);
    gl_lds16(sk1, KtB + (32 + wave * 8) * 64);
    gl_lds16(sv0, VtB + (wave * 8) * 64);
    gl_lds16(sv1, VtB + (32 + wave * 8) * 64);
    sk0 += 64 * 64; sk1 += 64 * 64;   // next K tile: +64 rows
    sv0 += 64;      sv1 += 64;        // next V tile: +64 cols
    if (tid < 128) {
      int t = tid & 63;
      if (tid < 64) kks[t] = kk[bh * 2048 + jt * 64 + t];
      else          lns[t] = -0.5f * lognc[bh * 2048 + jt * 64 + t];
    }
    __syncthreads();

    float4_t acc[4] = {};
    for (int nt = 0; nt < 4; nt++)
      for (int ks = 0; ks < 2; ks++) {
        half8 bfv = *(const half8*)(KtB + (size_t)(nt * 16 + l15) * 64 +
                                    (((ks * 4 + quad) ^ swq) * 8));
        acc[nt] = __builtin_amdgcn_mfma_f32_16x16x32_f16(af[ks], bfv, acc[nt], 0, 0, 0);
      }

    float mv[4][4];
    float lmx[4] = {-1e30f, -1e30f, -1e30f, -1e30f};
    for (int nt = 0; nt < 4; nt++) {
      float kn = kks[nt * 16 + l15];
      float bias = lns[nt * 16 + l15];
      for (int rg = 0; rg < 4; rg++) {
        float d2 = fmaxf(fmaf(-2.f, acc[nt][rg], qv[rg] + kn), 0.f);
        float g = fsqrt(d2);
        float m = fmaf(-PWR, flog2(1.f + g), bias);
        mv[nt][rg] = m;
        lmx[rg] = fmaxf(lmx[rg], m);
      }
    }
    bool noimp = (lmx[0] <= rm[0]) & (lmx[1] <= rm[1]) &
                 (lmx[2] <= rm[2]) & (lmx[3] <= rm[3]);
    if (!__all(noimp)) {   // rare: rescale
      for (int rg = 0; rg < 4; rg++) {
        float t = lmx[rg];
        for (int m = 1; m < 16; m <<= 1) t = fmaxf(t, __shfl_xor(t, m, 16));
        t = fmaxf(t, rm[rg]);
        float a = fexp2(rm[rg] - t);
        os[rg] *= a;
        Oacc[0][rg] *= a; Oacc[1][rg] *= a; Oacc[2][rg] *= a; Oacc[3][rg] *= a;
        rm[rg] = t;
      }
    }

    for (int nt = 0; nt < 4; nt++)
      for (int rg = 0; rg < 4; rg++) {
        float p = fexp2(mv[nt][rg] - rm[rg]);   // <= 1 guaranteed
        os[rg] += p;
        Pw[quad * 4 + rg][nt * 16 + l15] = (f16)p;
      }
    // no barrier: Pw is wave-private; lgkmcnt orders write->read

    for (int ks = 0; ks < 2; ks++) {
      half8 pa = *(const half8*)(&Pw[l15][ks * 32 + quad * 8]);
      for (int nt = 0; nt < 4; nt++) {
        half8 vbv = *(const half8*)(VtB + (size_t)(nt * 16 + l15) * 64 +
                                    (((ks * 4 + quad) ^ swq) * 8));
        Oacc[nt] = __builtin_amdgcn_mfma_f32_16x16x32_f16(pa, vbv, Oacc[nt], 0, 0, 0);
      }
    }
  }

  int b = bh / 12, h = bh - b * 12;
  for (int rg = 0; rg < 4; rg++) {
    float t = os[rg];
    for (int m = 1; m < 16; m <<= 1) t += __shfl_xor(t, m, 16);
    float inv = 1.f / t;
    int srow = i0 + wave * 16 + quad * 4 + rg;
    for (int nt = 0; nt < 4; nt++) {
      int d = nt * 16 + l15;
      attn[((size_t)(b * 2048 + srow)) * 768 + h * 64 + d] =
          (f16)(Oacc[nt][rg] * inv);
    }
  }
}

// ---------------------------------------------------------------------------
__global__ __launch_bounds__(256) void k_gemm_out(
    const f16* __restrict__ A, const f16* __restrict__ Bt,
    const float* __restrict__ bias, float* __restrict__ out) {
  __shared__ f16 As[128][72];
  __shared__ f16 Bs[128][72];
  int tid  = threadIdx.x;
  int wave = tid >> 6, lane = tid & 63;
  int quad = lane >> 4, l15 = lane & 15;
  int wm = wave >> 1, wn = wave & 1;
  int m0 = blockIdx.y * 128;
  int n0 = blockIdx.x * 128;

  float4_t acc[4][4] = {};
  int r  = tid >> 3;
  int c8 = (tid & 7) * 8;

  for (int k0 = 0; k0 < 768; k0 += 64) {
    for (int rr = 0; rr < 128; rr += 32) {
      *(uint4*)(&As[r + rr][c8]) =
          *(const uint4*)(A  + (size_t)(m0 + r + rr) * 768 + k0 + c8);
      *(uint4*)(&Bs[r + rr][c8]) =
          *(const uint4*)(Bt + (size_t)(n0 + r + rr) * 768 + k0 + c8);
    }
    __syncthreads();
    half8 af[4][2], bf[4][2];
    for (int mt = 0; mt < 4; mt++)
      for (int ks = 0; ks < 2; ks++)
        af[mt][ks] = *(const half8*)(&As[wm * 64 + mt * 16 + l15][ks * 32 + quad * 8]);
    for (int nt = 0; nt < 4; nt++)
      for (int ks = 0; ks < 2; ks++)
        bf[nt][ks] = *(const half8*)(&Bs[wn * 64 + nt * 16 + l15][ks * 32 + quad * 8]);
    for (int ks = 0; ks < 2; ks++)
      for (int mt = 0; mt < 4; mt++)
        for (int nt = 0; nt < 4; nt++)
          acc[mt][nt] = __builtin_amdgcn_mfma_f32_16x16x32_f16(af[mt][ks], bf[nt][ks],
                                                               acc[mt][nt], 0, 0, 0);
    __syncthreads();
  }

  for (int mt = 0; mt < 4; mt++)
    for (int nt = 0; nt < 4; nt++)
      for (int rg = 0; rg < 4; rg++) {
        int R = m0 + wm * 64 + mt * 16 + quad * 4 + rg;
        int n = n0 + wn * 64 + nt * 16 + l15;
        out[(size_t)R * 768 + n] = acc[mt][nt][rg] + bias[n];
      }
}

// ---------------------------------------------------------------------------
extern "C" void kernel_launch(void* const* d_in, const int* in_sizes, int n_in,
                              void* d_out, int out_size, void* d_ws, size_t ws_size,
                              hipStream_t stream) {
  const float* x     = (const float*)d_in[0];
  const float* Wqkv  = (const float*)d_in[1];
  const float* bqkv  = (const float*)d_in[2];
  const float* Wout  = (const float*)d_in[3];
  const float* bout  = (const float*)d_in[4];
  float* out = (float*)d_out;

  char* ws = (char*)d_ws;
  size_t off = 0;
  f16* xh     = (f16*)(ws + off);
  off += (size_t)M1_ * HID_ * 2;
  f16* wqkvt  = (f16*)(ws + off); off += (size_t)N1_ * HID_ * 2;
  f16* woutt  = (f16*)(ws + off); off += (size_t)HID_ * HID_ * 2;
  f16* Qh     = (f16*)(ws + off); off += (size_t)BH_ * S_ * D_ * 2;
  f16* Kh     = (f16*)(ws + off); off += (size_t)BH_ * S_ * D_ * 2;
  f16* Vt     = (f16*)(ws + off); off += (size_t)BH_ * S_ * D_ * 2;
  float* qq   = (float*)(ws + off); off += (size_t)BH_ * S_ * 4;
  float* kk   = (float*)(ws + off); off += (size_t)BH_ * S_ * 4;
  float* lognc= (float*)(ws + off); off += (size_t)BH_ * S_ * 4;
  f16* attn   = xh;  // xh dead after k_gemm_qkv

  k_convert_x<<<dim3(M1_ * HID_ / 4 / 256), dim3(256), 0, stream>>>(x, xh);
  k_transpose_w<<<dim3(9, 768), dim3(256), 0, stream>>>(Wqkv, wqkvt, N1_, HID_);
  k_transpose_w<<<dim3(3, 768), dim3(256), 0, stream>>>(Wout, woutt, HID_, HID_);

  k_gemm_qkv<<<dim3(N1_ / 128, M1_ / 128), dim3(256), 0, stream>>>(
      xh, wqkvt, bqkv, Qh, Kh, Vt);

  k_norms<<<dim3(BH_ * S_ / 256), dim3(256), 0, stream>>>(Qh, Kh, qq, kk);

  k_colsum<<<dim3(S_ / 64, BH_), dim3(256), 0, stream>>>(Qh, Kh, qq, kk, lognc);

  k_flash<<<dim3(S_ / 64, BH_), dim3(256), 0, stream>>>(
      Qh, Kh, Vt, qq, kk, lognc, attn);

  k_gemm_out<<<dim3(HID_ / 128, M1_ / 128), dim3(256), 0, stream>>>(
      attn, woutt, bout, out);
}